// Round 5
// baseline (836.412 us; speedup 1.0000x reference)
//
#include <hip/hip_runtime.h>
#include <hip/hip_bf16.h>
#include <stdint.h>

// Problem constants (from reference)
#define N_ENT    100000
#define N_REL    250000
#define N_TRIG   50000
#define N_ARGS   250000
#define ENT_DIM  288
#define REL_R    256
#define RTYPE_DIM 32
#define ROLE_DIM 256
#define ARG_DIM  576           // REL_R + RTYPE_DIM + ENT_DIM
#define OUT_DIM  544           // ENT_DIM + ROLE_DIM
#define REL_SIZE_PLUS1 201

// GEMM tiling
#define BM 64                  // args per block
#define BK 32                  // K chunk (one MFMA K-step)
#define NSTEP (ARG_DIM / BK)   // 18
#define LDPK 584               // full-K LDS row stride in shorts (576+8)
#define CSP 258                // Cs padded row stride (floats)

// bf16 table strides (shorts)
#define RELB_STRIDE 256        // 512 B rows
#define ENTB_STRIDE 320        // 640 B rows (576 B data + 64 B pad -> 128B mult)
#define RTB_STRIDE  32         // 64 B rows

typedef __attribute__((ext_vector_type(8))) short bf16x8;   // 8 bf16 (4 VGPRs)
typedef __attribute__((ext_vector_type(4))) short bf16x4;   // 4 bf16 (2 VGPRs)
typedef __attribute__((ext_vector_type(4))) float f32x4;    // MFMA acc / NT stores

// f32 -> bf16 (round-to-nearest-even), bit-level
__device__ __forceinline__ short f2b(float f) {
    union { float f; uint32_t u; } v; v.f = f;
    uint32_t u = v.u;
    uint32_t r = (u + 0x7fffu + ((u >> 16) & 1u)) >> 16;
    return (short)r;
}
__device__ __forceinline__ bf16x8 cvt8(float4 a, float4 b) {
    bf16x8 h;
    h[0] = f2b(a.x); h[1] = f2b(a.y); h[2] = f2b(a.z); h[3] = f2b(a.w);
    h[4] = f2b(b.x); h[5] = f2b(b.y); h[6] = f2b(b.z); h[7] = f2b(b.w);
    return h;
}

// ---------------------------------------------------------------------------
// Kernel 1: out[t, 0:288] = ent[trig_ent[t]];  out[t, 288:544] = 0.
// Nontemporal stores (ext_vector f32x4 — builtin rejects HIP float4 class).
__global__ void __launch_bounds__(256)
k_init(const float* __restrict__ ent, const int* __restrict__ trig_ent,
       float* __restrict__ out)
{
    const int t    = blockIdx.x * 4 + (threadIdx.x >> 6);
    const int lane = threadIdx.x & 63;
    const int e    = trig_ent[t];
    const f32x4* src = (const f32x4*)(ent + (size_t)e * ENT_DIM);  // 72 f4
    f32x4*       dst = (f32x4*)(out + (size_t)t * OUT_DIM);        // 136 f4
    const f32x4 z = {0.f, 0.f, 0.f, 0.f};
    __builtin_nontemporal_store(src[lane], &dst[lane]);            // 0..255
    if (lane < 8)
        __builtin_nontemporal_store(src[64 + lane], &dst[64 + lane]); // 256..287
    __builtin_nontemporal_store(z, &dst[72 + lane]);               // 288..543
}

// ---------------------------------------------------------------------------
// Kernel 2 (fused): W convert+transpose  AND  trigger histogram.
__global__ void __launch_bounds__(256)
k_prep_hist(const float* __restrict__ W_in, const float* __restrict__ W_out,
            short* __restrict__ Wb,
            const int* __restrict__ arg_trig, int* __restrict__ cnt)
{
    const int idx = blockIdx.x * 256 + threadIdx.x;     // 0 .. 294911
    {
        const int w   = idx / (ARG_DIM * ROLE_DIM);
        const int rem = idx % (ARG_DIM * ROLE_DIM);
        const int k   = rem / ROLE_DIM;
        const int col = rem % ROLE_DIM;
        const float* src = (w == 0) ? W_in : W_out;
        Wb[((size_t)w * ROLE_DIM + col) * ARG_DIM + k] = f2b(src[k * ROLE_DIM + col]);
    }
    if (idx < N_ARGS) atomicAdd(&cnt[arg_trig[idx]], 1);
}

// ---------------------------------------------------------------------------
// Kernel 2b: streaming f32 -> bf16 conversion of the gather tables.
// rel: dense [250000][256]; ent: padded [100000][320]; rtab: dense [201][32].
#define CONV_REL_BLOCKS 31250                    // 250000*256/(256*8)
#define CONV_ENT_ELEMS  (N_ENT * ENT_DIM)        // 28,800,000
#define CONV_ENT_BLOCKS 14063                    // ceil(28.8M/(256*8))
#define CONV_RT_BLOCKS  26                       // ceil(201*32/256)
#define CONV_BLOCKS (CONV_REL_BLOCKS + CONV_ENT_BLOCKS + CONV_RT_BLOCKS)

__global__ void __launch_bounds__(256)
k_conv(const float* __restrict__ rel, const float* __restrict__ ent,
       const float* __restrict__ rtab,
       short* __restrict__ relb, short* __restrict__ entb,
       short* __restrict__ rtb)
{
    const int b = blockIdx.x;
    if (b < CONV_REL_BLOCKS) {
        const int i = (b * 256 + threadIdx.x) * 8;          // < 64M
        float4 v0 = *(const float4*)(rel + i);
        float4 v1 = *(const float4*)(rel + i + 4);
        __builtin_nontemporal_store(cvt8(v0, v1), (bf16x8*)(relb + i));
    } else if (b < CONV_REL_BLOCKS + CONV_ENT_BLOCKS) {
        const int i = ((b - CONV_REL_BLOCKS) * 256 + threadIdx.x) * 8;
        if (i < CONV_ENT_ELEMS) {
            float4 v0 = *(const float4*)(ent + i);
            float4 v1 = *(const float4*)(ent + i + 4);
            const int row = i / ENT_DIM;
            const int col = i - row * ENT_DIM;              // multiple of 8
            __builtin_nontemporal_store(
                cvt8(v0, v1), (bf16x8*)(entb + (size_t)row * ENTB_STRIDE + col));
        }
    } else {
        const int i = (b - CONV_REL_BLOCKS - CONV_ENT_BLOCKS) * 256 + threadIdx.x;
        if (i < (REL_SIZE_PLUS1 * RTYPE_DIM)) rtb[i] = f2b(rtab[i]);
    }
}

// ---------------------------------------------------------------------------
// Counting sort (by trigger): scan1 -> scan3 -> scatter
#define SCAN_T 1024
#define SCAN_B ((N_TRIG + SCAN_T - 1) / SCAN_T)   // 49

__global__ void __launch_bounds__(SCAN_T)
k_scan1(const int* __restrict__ cnt, int* __restrict__ off,
        int* __restrict__ bsum)
{
    __shared__ int buf[SCAN_T];
    const int tid = threadIdx.x;
    const int i   = blockIdx.x * SCAN_T + tid;
    int v = (i < N_TRIG) ? cnt[i] : 0;
    buf[tid] = v;
    __syncthreads();
#pragma unroll
    for (int o = 1; o < SCAN_T; o <<= 1) {
        int x = (tid >= o) ? buf[tid - o] : 0;
        __syncthreads();
        buf[tid] += x;
        __syncthreads();
    }
    if (i < N_TRIG) off[i] = buf[tid] - v;          // block-local exclusive
    if (tid == SCAN_T - 1) bsum[blockIdx.x] = buf[tid];
}

__global__ void __launch_bounds__(SCAN_T)
k_scan3(int* __restrict__ off, const int* __restrict__ bsum)
{
    __shared__ int sh;
    if (threadIdx.x == 0) {
        int s = 0;
        for (int j = 0; j < (int)blockIdx.x; ++j) s += bsum[j];
        sh = s;
    }
    __syncthreads();
    const int i = blockIdx.x * SCAN_T + threadIdx.x;
    if (i < N_TRIG) off[i] += sh;
}

__global__ void __launch_bounds__(256)
k_scatter(const int* __restrict__ arg_trig, int* __restrict__ off,
          int* __restrict__ idx)
{
    const int a = blockIdx.x * 256 + threadIdx.x;
    if (a < N_ARGS) {
        const int p = atomicAdd(&off[arg_trig[a]], 1);
        idx[p] = a;
    }
}

// ---------------------------------------------------------------------------
// Kernel 3: fused gather + bf16 MFMA GEMM + segmented (sorted) reduction.
// BF16TAB=1: gather from pre-converted bf16 tables (half the bytes/segments,
// L3-resident working set, no f2b in staging). BF16TAB=0: R3 f32 fallback.
template<int BF16TAB>
__global__ void __launch_bounds__(512, 4)
k_gemm(const float* __restrict__ ent,  const float* __restrict__ rel,
       const float* __restrict__ rtab, const short* __restrict__ Wb,
       const short* __restrict__ relb, const short* __restrict__ entb,
       const short* __restrict__ rtb,
       const int* __restrict__ rtype_ids, const int* __restrict__ arg_trig,
       const int* __restrict__ arg_rel,   const int* __restrict__ arg_ent,
       const int* __restrict__ arg_is_in, const int* __restrict__ idx,
       float* __restrict__ out)
{
    __shared__ alignas(16) short As[BM][LDPK];   // 74,752 B; aliased by Cs
    __shared__ int s_rel[BM], s_ent[BM], s_rt[BM], s_trig[BM], s_mask[BM];

    const int tid = threadIdx.x;
    const int a0  = blockIdx.x * BM;

    if (tid < BM) {
        int i     = a0 + tid;
        int valid = (i < N_ARGS);
        int a     = idx[valid ? i : (N_ARGS - 1)];
        int r     = arg_rel[a];
        s_rel[tid]  = r;
        s_ent[tid]  = arg_ent[a];
        s_rt[tid]   = rtype_ids[r];
        s_trig[tid] = valid ? arg_trig[a] : -1;
        s_mask[tid] = valid ? arg_is_in[a] : -1;
    }
    __syncthreads();

    const int lane  = tid & 63;
    const int wave  = tid >> 6;          // 0..7
    const int quad  = lane >> 4;
    const int l15   = lane & 15;
    const int nbase = wave * 32;

    const int srow = tid >> 3;           // 0..63  (8 threads per row)
    const int sub  = tid & 7;

    if constexpr (BF16TAB) {
        // ---- burst-stage from bf16 tables: 8-10 x 16B loads, then ds_writes
        const short* q_rel = relb + (size_t)s_rel[srow] * RELB_STRIDE + sub * 8;
        const short* q_ent = entb + (size_t)s_ent[srow] * ENTB_STRIDE + sub * 8;
        const short* q_rt  = rtb  + s_rt[srow] * RTB_STRIDE + sub * 8;

        bf16x8 r0 = *(const bf16x8*)(q_rel);
        bf16x8 r1 = *(const bf16x8*)(q_rel + 64);
        bf16x8 r2 = *(const bf16x8*)(q_rel + 128);
        bf16x8 r3 = *(const bf16x8*)(q_rel + 192);
        bf16x8 e0 = *(const bf16x8*)(q_ent);
        bf16x8 e1 = *(const bf16x8*)(q_ent + 64);
        bf16x8 e2 = *(const bf16x8*)(q_ent + 128);
        bf16x8 e3 = *(const bf16x8*)(q_ent + 192);
        bf16x8 rt4, e4;
        if (sub < 4) {
            rt4 = *(const bf16x8*)(q_rt);
            e4  = *(const bf16x8*)(q_ent + 256);
        }
        *(bf16x8*)&As[srow][      sub * 8] = r0;
        *(bf16x8*)&As[srow][ 64 + sub * 8] = r1;
        *(bf16x8*)&As[srow][128 + sub * 8] = r2;
        *(bf16x8*)&As[srow][192 + sub * 8] = r3;
        *(bf16x8*)&As[srow][288 + sub * 8] = e0;
        *(bf16x8*)&As[srow][352 + sub * 8] = e1;
        *(bf16x8*)&As[srow][416 + sub * 8] = e2;
        *(bf16x8*)&As[srow][480 + sub * 8] = e3;
        if (sub < 4) {
            *(bf16x8*)&As[srow][256 + sub * 8] = rt4;
            *(bf16x8*)&As[srow][544 + sub * 8] = e4;
        }
    } else {
        // ---- R3 fallback: f32 burst-stage + convert ----
        const int skq = sub * 4;
        const float* p_rel = rel  + (size_t)s_rel[srow] * REL_R    + skq;
        const float* p_rt  = rtab + s_rt[srow] * RTYPE_DIM         + skq;
        const float* p_ent = ent  + (size_t)s_ent[srow] * ENT_DIM  + skq;
        {
            float4 t[9];
#pragma unroll
            for (int s = 0; s < 8; ++s) t[s] = *(const float4*)(p_rel + s * BK);
            t[8] = *(const float4*)p_rt;
#pragma unroll
            for (int s = 0; s < 9; ++s) {
                bf16x4 h;
                h[0] = f2b(t[s].x); h[1] = f2b(t[s].y);
                h[2] = f2b(t[s].z); h[3] = f2b(t[s].w);
                *(bf16x4*)&As[srow][s * BK + skq] = h;
            }
        }
        {
            float4 t[9];
#pragma unroll
            for (int s = 0; s < 9; ++s) t[s] = *(const float4*)(p_ent + s * BK);
#pragma unroll
            for (int s = 0; s < 9; ++s) {
                bf16x4 h;
                h[0] = f2b(t[s].x); h[1] = f2b(t[s].y);
                h[2] = f2b(t[s].z); h[3] = f2b(t[s].w);
                *(bf16x4*)&As[srow][(s + 9) * BK + skq] = h;
            }
        }
    }

    int rowmask[4];
#pragma unroll
    for (int m = 0; m < 4; ++m) rowmask[m] = s_mask[m * 16 + l15];

    f32x4 acc[4][2];
#pragma unroll
    for (int m = 0; m < 4; ++m)
#pragma unroll
        for (int n = 0; n < 2; ++n) acc[m][n] = (f32x4){0.f, 0.f, 0.f, 0.f};

    const short* wbl = Wb + (size_t)(nbase + l15) * ARG_DIM + quad * 8;
    const bf16x8 zf = {0, 0, 0, 0, 0, 0, 0, 0};

    __syncthreads();   // A panel fully staged

    // ---- barrier-free compute: 18 steps ----
#pragma unroll
    for (int s = 0; s < NSTEP; ++s) {
        const short* bp = wbl + s * BK;
        const bf16x8 bi0 = *(const bf16x8*)(bp);
        const bf16x8 bi1 = *(const bf16x8*)(bp + 16 * ARG_DIM);
        const bf16x8 bo0 = *(const bf16x8*)(bp + (size_t)ROLE_DIM * ARG_DIM);
        const bf16x8 bo1 = *(const bf16x8*)(bp + (size_t)(ROLE_DIM + 16) * ARG_DIM);

        bf16x8 a[4];
#pragma unroll
        for (int m = 0; m < 4; ++m)
            a[m] = *(const bf16x8*)&As[m * 16 + l15][s * BK + quad * 8];

#pragma unroll
        for (int m = 0; m < 4; ++m) {
            const bf16x8 ain = (rowmask[m] == 1) ? a[m] : zf;
            const bf16x8 aot = (rowmask[m] == 0) ? a[m] : zf;
            acc[m][0] = __builtin_amdgcn_mfma_f32_16x16x32_bf16(ain, bi0, acc[m][0], 0, 0, 0);
            acc[m][0] = __builtin_amdgcn_mfma_f32_16x16x32_bf16(aot, bo0, acc[m][0], 0, 0, 0);
            acc[m][1] = __builtin_amdgcn_mfma_f32_16x16x32_bf16(ain, bi1, acc[m][1], 0, 0, 0);
            acc[m][1] = __builtin_amdgcn_mfma_f32_16x16x32_bf16(aot, bo1, acc[m][1], 0, 0, 0);
        }
    }

    // ---- epilogue phase 1: stage accumulator tile into Cs (aliases As) ----
    __syncthreads();
    float (*Cs)[CSP] = (float(*)[CSP])&As[0][0];   // 66,048 B <= 74,752 B
#pragma unroll
    for (int m = 0; m < 4; ++m)
#pragma unroll
        for (int n = 0; n < 2; ++n)
#pragma unroll
            for (int r4 = 0; r4 < 4; ++r4)
                Cs[m * 16 + quad * 4 + r4][nbase + n * 16 + l15] = acc[m][n][r4];
    __syncthreads();

    // ---- epilogue phase 2: segmented run-reduction (rows sorted by trig) ----
    {
        const int c    = tid & 255;
        const int half = tid >> 8;               // 0 or 1
        const int r0   = half * 32;
        const int rend = r0 + 32;

        int   runTrig  = s_trig[r0];
        int   runStart = r0;
        float sum      = 0.f;
        for (int r = r0; r < rend; ++r) {
            const int t = s_trig[r];
            if (t != runTrig) {
                if (runTrig >= 0) {
                    float* p = out + (size_t)runTrig * OUT_DIM + ENT_DIM + c;
                    if (runStart == r0) atomicAdd(p, sum);   // may extend left
                    else                *p = sum;            // complete sum
                }
                runTrig = t; runStart = r; sum = 0.f;
            }
            sum += Cs[r][c];
        }
        if (runTrig >= 0) {
            float* p = out + (size_t)runTrig * OUT_DIM + ENT_DIM + c;
            atomicAdd(p, sum);                               // may extend right
        }
    }
}

// ---------------------------------------------------------------------------
extern "C" void kernel_launch(void* const* d_in, const int* in_sizes, int n_in,
                              void* d_out, int out_size, void* d_ws, size_t ws_size,
                              hipStream_t stream)
{
    const float* ent      = (const float*)d_in[0];   // [N_ENT, 288]
    const float* rel      = (const float*)d_in[1];   // [N_REL, 256]
    const float* rtab     = (const float*)d_in[2];   // [201, 32]
    const float* W_in     = (const float*)d_in[3];   // [576, 256]
    const float* W_out    = (const float*)d_in[4];   // [576, 256]
    const int*  rtype_ids = (const int*)d_in[5];
    const int*  trig_ent  = (const int*)d_in[6];
    const int*  arg_trig  = (const int*)d_in[7];
    const int*  arg_rel   = (const int*)d_in[8];
    const int*  arg_ent   = (const int*)d_in[9];
    const int*  arg_is_in = (const int*)d_in[10];

    float* out = (float*)d_out;                      // [N_TRIG, 544] f32

    // Workspace layout (bytes):
    //   Wb   : [0, 589824)              bf16 [2][256][576]
    //   cnt  : [589824, 789824)         int [50000]
    //   off  : [789824, 989824)         int [50000]
    //   bsum : [989824, 990080)         int [49] (padded)
    //   idx  : [990080, 1990080)        int [250000]
    //   rtb  : [1990080, 2002944)       bf16 [201][32]
    //   relb : [2002944, 130002944)     bf16 [250000][256]
    //   entb : [130002944, 194002944)   bf16 [100000][320]
    char* ws   = (char*)d_ws;
    short* Wb  = (short*)(ws);
    int*   cnt = (int*)(ws + 589824);
    int*   off = (int*)(ws + 789824);
    int*   bsum= (int*)(ws + 989824);
    int*   idx = (int*)(ws + 990080);
    short* rtb = (short*)(ws + 1990080);
    short* relb= (short*)(ws + 2002944);
    short* entb= (short*)(ws + 130002944ULL);

    const bool bf16tabs = (ws_size >= 194002944ULL);

    (void)hipMemsetAsync(cnt, 0, 200000, stream);

    hipLaunchKernelGGL(k_init, dim3(N_TRIG / 4), dim3(256), 0, stream,
                       ent, trig_ent, out);
    hipLaunchKernelGGL(k_prep_hist, dim3(2 * ARG_DIM * ROLE_DIM / 256), dim3(256),
                       0, stream, W_in, W_out, Wb, arg_trig, cnt);
    if (bf16tabs)
        hipLaunchKernelGGL(k_conv, dim3(CONV_BLOCKS), dim3(256), 0, stream,
                           rel, ent, rtab, relb, entb, rtb);
    hipLaunchKernelGGL(k_scan1, dim3(SCAN_B), dim3(SCAN_T), 0, stream,
                       cnt, off, bsum);
    hipLaunchKernelGGL(k_scan3, dim3(SCAN_B), dim3(SCAN_T), 0, stream,
                       off, bsum);
    hipLaunchKernelGGL(k_scatter, dim3((N_ARGS + 255) / 256), dim3(256), 0,
                       stream, arg_trig, off, idx);
    if (bf16tabs)
        hipLaunchKernelGGL(k_gemm<1>, dim3((N_ARGS + BM - 1) / BM), dim3(512), 0,
                           stream, ent, rel, rtab, Wb, relb, entb, rtb,
                           rtype_ids, arg_trig, arg_rel, arg_ent, arg_is_in, idx, out);
    else
        hipLaunchKernelGGL(k_gemm<0>, dim3((N_ARGS + BM - 1) / BM), dim3(512), 0,
                           stream, ent, rel, rtab, Wb, relb, entb, rtb,
                           rtype_ids, arg_trig, arg_rel, arg_ent, arg_is_in, idx, out);
}